// Round 18
// baseline (109.291 us; speedup 1.0000x reference)
//
#include <hip/hip_runtime.h>

#define DIM 128
#define SB_SHIFT 9        // 512 rows per superbucket
#define SB_ROWS 512
#define SBCAP 10240       // chunk capacity per superbucket (E[cnt]=8192, +22 sigma)
#define TILE1 4096        // edges per partition block

typedef short bf16x8 __attribute__((ext_vector_type(8)));
typedef float f32x4  __attribute__((ext_vector_type(4)));

__device__ inline unsigned int f2b(float f) {  // fp32 -> bf16 RNE
  unsigned int u = __float_as_uint(f);
  unsigned int r = u + 0x7FFFu + ((u >> 16) & 1u);
  return r >> 16;
}
__device__ inline unsigned int f2b2(float lo, float hi) {  // pack 2 bf16
  return f2b(lo) | (f2b(hi) << 16);
}
__device__ inline void cvt8(const float* __restrict__ src, unsigned short* dst,
                            size_t i8) {
  const float4* xp = reinterpret_cast<const float4*>(src) + i8 * 2;
  float4 a = xp[0], c = xp[1];
  uint4 o;
  o.x = f2b2(a.x, a.y);
  o.y = f2b2(a.z, a.w);
  o.z = f2b2(c.x, c.y);
  o.w = f2b2(c.z, c.w);
  reinterpret_cast<uint4*>(dst)[i8] = o;
}
__device__ inline unsigned int q4(float a, float b, float c, float d, float inv) {
  int qa = (int)rintf(a * inv), qb = (int)rintf(b * inv);
  int qc = (int)rintf(c * inv), qd = (int)rintf(d * inv);
  return ((unsigned int)(qa & 255)) | ((unsigned int)(qb & 255) << 8) |
         ((unsigned int)(qc & 255) << 16) | ((unsigned int)(qd & 255) << 24);
}

// ============ part1: edge partition into superbucket chunks ================
// 512 threads (8 waves); 44KB LDS -> 3 blocks/CU.
// gL1 entry: x = rowlo(9)<<17 | col(17),  y = wq = round(w*32768) in [0,32767]
__global__ __launch_bounds__(512) void part1(
    const int* __restrict__ erow, const int* __restrict__ ecol,
    const float* __restrict__ ew, int* __restrict__ cnt,
    int2* __restrict__ gL1, int E, int NSB) {
  __shared__ int2 stage[TILE1];
  __shared__ unsigned short sbid[TILE1];
  __shared__ int lcnt[256], loff[256], gbs[256], stmp[256];

  const int t = threadIdx.x;
  const int base = blockIdx.x * TILE1;
  const int ntile = min(TILE1, E - base);

  if (t < 256) lcnt[t] = 0;
  __syncthreads();

  int rk[TILE1 / 512];
#pragma unroll
  for (int i = 0; i < TILE1 / 512; ++i) {
    int e = base + t + i * 512;
    rk[i] = -1;
    if (e < E) {
      int bkt = erow[e] >> SB_SHIFT;
      rk[i] = atomicAdd(&lcnt[bkt], 1);
    }
  }
  __syncthreads();

  int myc = (t < 256) ? lcnt[t] : 0;
  if (t < 256) stmp[t] = myc;
  __syncthreads();
  for (int d = 1; d < 256; d <<= 1) {
    int val = 0;
    if (t < 256 && t >= d) val = stmp[t - d];
    __syncthreads();
    if (t < 256) stmp[t] += val;
    __syncthreads();
  }
  if (t < 256) loff[t] = stmp[t] - myc;
  if (t < NSB && myc > 0) gbs[t] = atomicAdd(&cnt[t], myc);  // relative base
  __syncthreads();

#pragma unroll
  for (int i = 0; i < TILE1 / 512; ++i) {
    int e = base + t + i * 512;
    if (e < E) {
      int row = erow[e];
      int bkt = row >> SB_SHIFT;
      int slot = loff[bkt] + rk[i];
      int wq = (int)(ew[e] * 32768.f + 0.5f);
      wq = min(wq, 32767);
      stage[slot] = make_int2(((row & (SB_ROWS - 1)) << 17) | ecol[e], wq);
      sbid[slot] = (unsigned short)bkt;
    }
  }
  __syncthreads();

  for (int s = t; s < ntile; s += 512) {
    int bkt = sbid[s];
    int rel = gbs[bkt] + (s - loff[bkt]);
    if (rel < SBCAP)  // overflow guard (statistically never)
      gL1[(size_t)bkt * SBCAP + rel] = stage[s];
  }
}

// == part2prep: [part2 CSR build] || [W->bf16] || [x int8 quant], by range ==
// First NSB blocks: per-superbucket local hist+scan+placement (6KB LDS only).
// Remaining blocks: streaming conversions — fills part2's latency bubbles.
__global__ __launch_bounds__(512) void part2prep(
    const int2* __restrict__ gL1, const int* __restrict__ cnt,
    int* __restrict__ off, int* __restrict__ deg,
    unsigned int* __restrict__ sedge, int N,
    const float* __restrict__ W, unsigned short* __restrict__ Wb,
    const float* __restrict__ x, unsigned int* __restrict__ xq,
    float* __restrict__ scale, int nelem8, int NSB, int ncw) {
  const int bid = (int)blockIdx.x;
  const int t = threadIdx.x;

  if (bid < NSB) {
    // ---- part2: local hist+scan+CSR placement ----
    __shared__ int hist[SB_ROWS];
    __shared__ int scn[SB_ROWS];
    __shared__ int cur[SB_ROWS];
    const int srow = bid << SB_SHIFT;
    const int start = bid * SBCAP;
    const int end = start + min(cnt[bid], SBCAP);

    hist[t] = 0;
    __syncthreads();
    for (int i = start + t; i < end; i += 512)
      atomicAdd(&hist[((unsigned)gL1[i].x) >> 17], 1);
    __syncthreads();

    int v = hist[t];
    scn[t] = v;
    __syncthreads();
    for (int d = 1; d < SB_ROWS; d <<= 1) {
      int val = (t >= d) ? scn[t - d] : 0;
      __syncthreads();
      scn[t] += val;
      __syncthreads();
    }
    int o = start + scn[t] - v;
    cur[t] = o;
    int row = srow + t;
    if (row < N) {
      off[row] = o;
      deg[row] = v;
    }
    __syncthreads();

    for (int i = start + t; i < end; i += 512) {
      int2 p = gL1[i];
      int rowlo = ((unsigned)p.x) >> 17;
      int dst = atomicAdd(&cur[rowlo], 1);
      sedge[dst] = ((unsigned int)p.x & 0x1FFFFu) | ((unsigned int)p.y << 17);
    }
    return;
  }

  if (bid < NSB + ncw) {
    int i = (bid - NSB) * 512 + t;         // DIM*DIM/8 = 2048 units
    if (i < DIM * DIM / 8) cvt8(W, Wb, i);
    return;
  }

  // ---- x int8 row-quant ----
  int i = (bid - NSB - ncw) * 512 + t;     // 8-elem unit; 16 units per row
  if (i >= nelem8) return;

  const float4* xp = reinterpret_cast<const float4*>(x) + (size_t)i * 2;
  float4 a = xp[0], c = xp[1];

  float m = fmaxf(fmaxf(fmaxf(fabsf(a.x), fabsf(a.y)), fmaxf(fabsf(a.z), fabsf(a.w))),
                  fmaxf(fmaxf(fabsf(c.x), fabsf(c.y)), fmaxf(fabsf(c.z), fabsf(c.w))));
#pragma unroll
  for (int d = 1; d < 16; d <<= 1) m = fmaxf(m, __shfl_xor(m, d));

  float inv = (m > 0.f) ? 127.f / m : 0.f;
  uint2 q;
  q.x = q4(a.x, a.y, a.z, a.w, inv);
  q.y = q4(c.x, c.y, c.z, c.w, inv);
  reinterpret_cast<uint2*>(xq)[i] = q;
  if ((t & 15) == 0) scale[i >> 4] = (m > 0.f) ? m / 127.f : 0.f;
}

// ====== aggregate2: g[r] = bf16( sum_e w * dequant(xq[col]) ) ==============
// 8 lanes/row, 16B uint4 gathers, 32 rows/block, 4-deep MLP.
__global__ __launch_bounds__(256) void aggregate2(
    const unsigned int* __restrict__ xq, const float* __restrict__ scale,
    const int* __restrict__ off, const int* __restrict__ deg,
    const unsigned int* __restrict__ sedge,
    unsigned short* __restrict__ g, int N) {
  const int r = (blockIdx.x * 256 + threadIdx.x) >> 3;
  const int l = threadIdx.x & 7;
  if (r >= N) return;

  const int start = off[r];
  const int n = deg[r];

  float acc[16];
#pragma unroll
  for (int i = 0; i < 16; ++i) acc[i] = 0.f;

#define GATHER(pp) (*reinterpret_cast<const uint4*>(xq + (size_t)((pp) & 0x1FFFFu) * 32 + l * 4))
#define FEDGE(pp) ((float)((pp) >> 17) * (1.0f / 32768.f) * scale[(pp) & 0x1FFFFu])
#define ACC4(w_, qw, base)                                                 \
  {                                                                        \
    acc[base + 0] += w_ * (float)(signed char)((qw));                      \
    acc[base + 1] += w_ * (float)(signed char)((qw) >> 8);                 \
    acc[base + 2] += w_ * (float)(signed char)((qw) >> 16);                \
    acc[base + 3] += w_ * (float)(signed char)((qw) >> 24);                \
  }
#define ACCUM(qv, fv)                                                      \
  {                                                                        \
    float f_ = (fv);                                                       \
    ACC4(f_, (qv).x, 0);                                                   \
    ACC4(f_, (qv).y, 4);                                                   \
    ACC4(f_, (qv).z, 8);                                                   \
    ACC4(f_, (qv).w, 12);                                                  \
  }

  int j = 0;
  for (; j + 4 <= n; j += 4) {
    unsigned int p0 = sedge[start + j];
    unsigned int p1 = sedge[start + j + 1];
    unsigned int p2 = sedge[start + j + 2];
    unsigned int p3 = sedge[start + j + 3];
    uint4 h0 = GATHER(p0);
    uint4 h1 = GATHER(p1);
    uint4 h2 = GATHER(p2);
    uint4 h3 = GATHER(p3);
    float f0 = FEDGE(p0);
    float f1 = FEDGE(p1);
    float f2 = FEDGE(p2);
    float f3 = FEDGE(p3);
    ACCUM(h0, f0);
    ACCUM(h1, f1);
    ACCUM(h2, f2);
    ACCUM(h3, f3);
  }
  for (; j < n; ++j) {
    unsigned int p = sedge[start + j];
    uint4 hv = GATHER(p);
    ACCUM(hv, FEDGE(p));
  }
#undef GATHER
#undef FEDGE
#undef ACC4
#undef ACCUM

  uint4 o0, o1;
  o0.x = f2b2(acc[0], acc[1]);
  o0.y = f2b2(acc[2], acc[3]);
  o0.z = f2b2(acc[4], acc[5]);
  o0.w = f2b2(acc[6], acc[7]);
  o1.x = f2b2(acc[8], acc[9]);
  o1.y = f2b2(acc[10], acc[11]);
  o1.z = f2b2(acc[12], acc[13]);
  o1.w = f2b2(acc[14], acc[15]);
  uint4* gp = reinterpret_cast<uint4*>(g + (size_t)r * DIM + l * 16);
  gp[0] = o0;
  gp[1] = o1;
}

// == gemm2: out = lrelu( g @ W^T + b + dequant(xq) ), MFMA bf16 =============
__global__ __launch_bounds__(256) void gemm2(
    const unsigned short* __restrict__ g, const unsigned short* __restrict__ Wb,
    const float* __restrict__ b, const unsigned int* __restrict__ xq,
    const float* __restrict__ scale, float* __restrict__ out, int N) {
  __shared__ unsigned short Ws[DIM * DIM];  // 32 KB

  const int t = threadIdx.x;
#pragma unroll
  for (int i = 0; i < 8; ++i) {
    int idx = i * 256 + t;            // 16B-unit index, 0..2047
    int row = idx >> 4;
    int slot = idx & 15;
    uint4 v = reinterpret_cast<const uint4*>(Wb)[idx];
    reinterpret_cast<uint4*>(Ws)[row * 16 + (slot ^ (row & 7))] = v;
  }
  __syncthreads();

  const int wid  = t >> 6;
  const int lane = t & 63;
  const int m0   = blockIdx.x * 64 + wid * 16;
  const int mrow = m0 + (lane & 15);
  const int koff = (lane >> 4) * 8;
  const int arow = (mrow < N) ? mrow : N - 1;

  f32x4 acc[8];
#pragma unroll
  for (int j = 0; j < 8; ++j) acc[j] = (f32x4){0.f, 0.f, 0.f, 0.f};

#pragma unroll
  for (int k0 = 0; k0 < DIM; k0 += 32) {
    bf16x8 af = *reinterpret_cast<const bf16x8*>(g + (size_t)arow * DIM + k0 + koff);
    const int slotbase = (k0 >> 3) + (lane >> 4);
#pragma unroll
    for (int j = 0; j < 8; ++j) {
      int row = j * 16 + (lane & 15);
      const uint4* wp = reinterpret_cast<const uint4*>(Ws) +
                        row * 16 + (slotbase ^ (row & 7));
      bf16x8 bf = *reinterpret_cast<const bf16x8*>(wp);
      acc[j] = __builtin_amdgcn_mfma_f32_16x16x32_bf16(af, bf, acc[j], 0, 0, 0);
    }
  }

  const int rowbase = (lane >> 4) * 4;
  float sq[4];
#pragma unroll
  for (int i = 0; i < 4; ++i) {
    int m = m0 + rowbase + i;
    sq[i] = (m < N) ? scale[m] : 0.f;
  }
#pragma unroll
  for (int j = 0; j < 8; ++j) {
    int n = j * 16 + (lane & 15);
    float bias = b[n];
#pragma unroll
    for (int i = 0; i < 4; ++i) {
      int m = m0 + rowbase + i;
      if (m < N) {
        unsigned int w = xq[(size_t)m * 32 + (n >> 2)];
        float res = (float)(signed char)(w >> ((n & 3) * 8)) * sq[i];
        float v = acc[j][i] + bias + res;
        out[(size_t)m * DIM + n] = v > 0.f ? v : 0.2f * v;
      }
    }
  }
}

// ===========================================================================
extern "C" void kernel_launch(void* const* d_in, const int* in_sizes, int n_in,
                              void* d_out, int out_size, void* d_ws,
                              size_t ws_size, hipStream_t stream) {
  const float* x  = (const float*)d_in[0];
  const int* erow = (const int*)d_in[1];
  const int* ecol = (const int*)d_in[2];
  const float* ew = (const float*)d_in[3];
  const float* W  = (const float*)d_in[4];
  const float* b  = (const float*)d_in[5];
  float* out      = (float*)d_out;

  const int N = in_sizes[0] / DIM;
  const int E = in_sizes[1];
  const int NSB = (N + SB_ROWS - 1) >> SB_SHIFT;  // 196 for N=100000
  const int netile = (E + TILE1 - 1) / TILE1;

  char* wsp = (char*)d_ws;
  unsigned int* xq   = (unsigned int*)wsp;    wsp += (size_t)N * DIM;            // int8
  float* scale = (float*)wsp;                 wsp += (size_t)N * sizeof(float);
  unsigned short* g  = (unsigned short*)wsp;  wsp += (size_t)N * DIM * sizeof(unsigned short);
  int*   off   = (int*)wsp;                   wsp += (size_t)N * sizeof(int);
  int*   deg   = (int*)wsp;                   wsp += (size_t)N * sizeof(int);
  int*   cnt   = (int*)wsp;                   wsp += 4096;
  unsigned short* Wb = (unsigned short*)wsp;  wsp += DIM * DIM * sizeof(unsigned short);
  int2*  gL1   = (int2*)wsp;                  wsp += (size_t)NSB * SBCAP * sizeof(int2);
  unsigned int* sedge = (unsigned int*)wsp;   wsp += (size_t)NSB * SBCAP * sizeof(unsigned int);

  hipMemsetAsync(cnt, 0, 4096, stream);

  part1<<<netile, 512, 0, stream>>>(erow, ecol, ew, cnt, gL1, E, NSB);

  // merged: part2 (NSB blocks) | W conv (ncw) | x quant (nxq)
  const int nelem8 = N * DIM / 8;
  const int ncw = (DIM * DIM / 8 + 511) / 512;   // 4
  const int nxq = (nelem8 + 511) / 512;
  part2prep<<<NSB + ncw + nxq, 512, 0, stream>>>(gL1, cnt, off, deg, sedge, N,
                                                 W, Wb, x, xq, scale,
                                                 nelem8, NSB, ncw);

  aggregate2<<<(N + 31) / 32, 256, 0, stream>>>(xq, scale, off, deg, sedge, g, N);

  gemm2<<<(N + 63) / 64, 256, 0, stream>>>(g, Wb, b, xq, scale, out, N);
}

// Round 19
// 107.324 us; speedup vs baseline: 1.0183x; 1.0183x over previous
//
#include <hip/hip_runtime.h>

#define DIM 128
#define SB_SHIFT 9        // 512 rows per superbucket
#define SB_ROWS 512
#define SBCAP 10240       // chunk capacity per superbucket (E[cnt]=8192, +22 sigma)
#define TILE1 4096        // edges per partition block
#define REG_E 18          // part2 register-held edges per thread (covers 9216)

typedef short bf16x8 __attribute__((ext_vector_type(8)));
typedef float f32x4  __attribute__((ext_vector_type(4)));

__device__ inline unsigned int f2b(float f) {  // fp32 -> bf16 RNE
  unsigned int u = __float_as_uint(f);
  unsigned int r = u + 0x7FFFu + ((u >> 16) & 1u);
  return r >> 16;
}
__device__ inline unsigned int f2b2(float lo, float hi) {  // pack 2 bf16
  return f2b(lo) | (f2b(hi) << 16);
}
__device__ inline void cvt8(const float* __restrict__ src, unsigned short* dst,
                            size_t i8) {
  const float4* xp = reinterpret_cast<const float4*>(src) + i8 * 2;
  float4 a = xp[0], c = xp[1];
  uint4 o;
  o.x = f2b2(a.x, a.y);
  o.y = f2b2(a.z, a.w);
  o.z = f2b2(c.x, c.y);
  o.w = f2b2(c.z, c.w);
  reinterpret_cast<uint4*>(dst)[i8] = o;
}
__device__ inline unsigned int q4(float a, float b, float c, float d, float inv) {
  int qa = (int)rintf(a * inv), qb = (int)rintf(b * inv);
  int qc = (int)rintf(c * inv), qd = (int)rintf(d * inv);
  return ((unsigned int)(qa & 255)) | ((unsigned int)(qb & 255) << 8) |
         ((unsigned int)(qc & 255) << 16) | ((unsigned int)(qd & 255) << 24);
}

// == prep_all: [W->bf16] || [x int8 rowquant] || [cnt=0], by block range =====
__global__ __launch_bounds__(256) void prep_all(
    const float* __restrict__ W, unsigned short* __restrict__ Wb,
    const float* __restrict__ x,
    unsigned int* __restrict__ xq, float* __restrict__ scale,
    int* __restrict__ cnt, int nelem8, int ncw, int nxb) {
  const int bid = (int)blockIdx.x;
  const int t = threadIdx.x;
  if (bid < ncw) {
    int i = bid * 256 + t;                 // DIM*DIM/8 = 2048 units
    if (i < DIM * DIM / 8) cvt8(W, Wb, i);
    return;
  }
  if (bid == ncw + nxb) {                  // zero superbucket counters
#pragma unroll
    for (int k = 0; k < 4; ++k) cnt[t * 4 + k] = 0;
    return;
  }
  int i = (bid - ncw) * 256 + t;           // 8-elem unit; 16 units per row
  if (i >= nelem8) return;

  const float4* xp = reinterpret_cast<const float4*>(x) + (size_t)i * 2;
  float4 a = xp[0], c = xp[1];

  float m = fmaxf(fmaxf(fmaxf(fabsf(a.x), fabsf(a.y)), fmaxf(fabsf(a.z), fabsf(a.w))),
                  fmaxf(fmaxf(fabsf(c.x), fabsf(c.y)), fmaxf(fabsf(c.z), fabsf(c.w))));
#pragma unroll
  for (int d = 1; d < 16; d <<= 1) m = fmaxf(m, __shfl_xor(m, d));

  float inv = (m > 0.f) ? 127.f / m : 0.f;
  uint2 q;
  q.x = q4(a.x, a.y, a.z, a.w, inv);
  q.y = q4(c.x, c.y, c.z, c.w, inv);
  reinterpret_cast<uint2*>(xq)[i] = q;
  if ((t & 15) == 0) scale[i >> 4] = (m > 0.f) ? m / 127.f : 0.f;
}

// ============ part1: edge partition into superbucket chunks ================
// Single global read of edges; rank pass + stage pass both from registers.
// gL1 entry: x = rowlo(9)<<17 | col(17),  y = wq = round(w*32768).
__global__ __launch_bounds__(512) void part1(
    const int* __restrict__ erow, const int* __restrict__ ecol,
    const float* __restrict__ ew, int* __restrict__ cnt,
    int2* __restrict__ gL1, int E, int NSB) {
  __shared__ int2 stage[TILE1];
  __shared__ unsigned short sbid[TILE1];
  __shared__ int lcnt[256], loff[256], gbs[256], stmp[256];

  const int t = threadIdx.x;
  const int base = blockIdx.x * TILE1;
  const int ntile = min(TILE1, E - base);

  if (t < 256) lcnt[t] = 0;
  __syncthreads();

  int rk[TILE1 / 512], bkt[TILE1 / 512], av[TILE1 / 512], wqv[TILE1 / 512];
#pragma unroll
  for (int i = 0; i < TILE1 / 512; ++i) {
    int e = base + t + i * 512;
    rk[i] = -1;
    if (e < E) {
      int row = erow[e];
      int col = ecol[e];
      float w = ew[e];
      int b_ = row >> SB_SHIFT;
      bkt[i] = b_;
      av[i] = ((row & (SB_ROWS - 1)) << 17) | col;
      int wq = (int)(w * 32768.f + 0.5f);
      wqv[i] = min(wq, 32767);
      rk[i] = atomicAdd(&lcnt[b_], 1);
    }
  }
  __syncthreads();

  int myc = (t < 256) ? lcnt[t] : 0;
  if (t < 256) stmp[t] = myc;
  __syncthreads();
  for (int d = 1; d < 256; d <<= 1) {
    int val = 0;
    if (t < 256 && t >= d) val = stmp[t - d];
    __syncthreads();
    if (t < 256) stmp[t] += val;
    __syncthreads();
  }
  if (t < 256) loff[t] = stmp[t] - myc;
  if (t < NSB && myc > 0) gbs[t] = atomicAdd(&cnt[t], myc);  // relative base
  __syncthreads();

#pragma unroll
  for (int i = 0; i < TILE1 / 512; ++i) {
    if (rk[i] >= 0) {
      int slot = loff[bkt[i]] + rk[i];
      stage[slot] = make_int2(av[i], wqv[i]);
      sbid[slot] = (unsigned short)bkt[i];
    }
  }
  __syncthreads();

  for (int s = t; s < ntile; s += 512) {
    int b_ = sbid[s];
    int rel = gbs[b_] + (s - loff[b_]);
    if (rel < SBCAP)  // overflow guard (statistically never)
      gL1[(size_t)b_ * SBCAP + rel] = stage[s];
  }
}

// ==== part2: local hist+scan+CSR placement per superbucket (chunked) =======
// Edges held in registers across hist->placement (single gL1 read).
// sedge entry: u32 = col(17) | wq(15)<<17.
__global__ __launch_bounds__(512) void part2(
    const int2* __restrict__ gL1, const int* __restrict__ cnt,
    int* __restrict__ off, int* __restrict__ deg,
    unsigned int* __restrict__ sedge, int N) {
  __shared__ int hist[SB_ROWS];
  __shared__ int scn[SB_ROWS];
  __shared__ int cur[SB_ROWS];
  const int t = threadIdx.x;
  const int srow = blockIdx.x << SB_SHIFT;
  const int start = blockIdx.x * SBCAP;
  const int end = start + min(cnt[blockIdx.x], SBCAP);
  const int regend = min(end, start + REG_E * 512);

  hist[t] = 0;
  __syncthreads();

  int2 er[REG_E];
#pragma unroll
  for (int k = 0; k < REG_E; ++k) {
    int i = start + t + k * 512;
    if (i < end) {
      int2 p = gL1[i];
      er[k] = p;
      atomicAdd(&hist[((unsigned)p.x) >> 17], 1);
    }
  }
  // fallback for cnt > REG_E*512 (statistically never)
  for (int i = start + REG_E * 512 + t; i < end; i += 512)
    atomicAdd(&hist[((unsigned)gL1[i].x) >> 17], 1);
  __syncthreads();

  int v = hist[t];
  scn[t] = v;
  __syncthreads();
  for (int d = 1; d < SB_ROWS; d <<= 1) {
    int val = (t >= d) ? scn[t - d] : 0;
    __syncthreads();
    scn[t] += val;
    __syncthreads();
  }
  int o = start + scn[t] - v;
  cur[t] = o;
  int row = srow + t;
  if (row < N) {
    off[row] = o;
    deg[row] = v;
  }
  __syncthreads();

#pragma unroll
  for (int k = 0; k < REG_E; ++k) {
    int i = start + t + k * 512;
    if (i < regend) {
      int2 p = er[k];
      int rowlo = ((unsigned)p.x) >> 17;
      int dst = atomicAdd(&cur[rowlo], 1);
      sedge[dst] = ((unsigned int)p.x & 0x1FFFFu) | ((unsigned int)p.y << 17);
    }
  }
  for (int i = start + REG_E * 512 + t; i < end; i += 512) {
    int2 p = gL1[i];
    int rowlo = ((unsigned)p.x) >> 17;
    int dst = atomicAdd(&cur[rowlo], 1);
    sedge[dst] = ((unsigned int)p.x & 0x1FFFFu) | ((unsigned int)p.y << 17);
  }
}

// ====== aggregate2: g[r] = bf16( sum_e w * dequant(xq[col]) ) ==============
// 8 lanes/row, 16B uint4 gathers, 32 rows/block, 4-deep MLP.
__global__ __launch_bounds__(256) void aggregate2(
    const unsigned int* __restrict__ xq, const float* __restrict__ scale,
    const int* __restrict__ off, const int* __restrict__ deg,
    const unsigned int* __restrict__ sedge,
    unsigned short* __restrict__ g, int N) {
  const int r = (blockIdx.x * 256 + threadIdx.x) >> 3;
  const int l = threadIdx.x & 7;
  if (r >= N) return;

  const int start = off[r];
  const int n = deg[r];

  float acc[16];
#pragma unroll
  for (int i = 0; i < 16; ++i) acc[i] = 0.f;

#define GATHER(pp) (*reinterpret_cast<const uint4*>(xq + (size_t)((pp) & 0x1FFFFu) * 32 + l * 4))
#define FEDGE(pp) ((float)((pp) >> 17) * (1.0f / 32768.f) * scale[(pp) & 0x1FFFFu])
#define ACC4(w_, qw, base)                                                 \
  {                                                                        \
    acc[base + 0] += w_ * (float)(signed char)((qw));                      \
    acc[base + 1] += w_ * (float)(signed char)((qw) >> 8);                 \
    acc[base + 2] += w_ * (float)(signed char)((qw) >> 16);                \
    acc[base + 3] += w_ * (float)(signed char)((qw) >> 24);                \
  }
#define ACCUM(qv, fv)                                                      \
  {                                                                        \
    float f_ = (fv);                                                       \
    ACC4(f_, (qv).x, 0);                                                   \
    ACC4(f_, (qv).y, 4);                                                   \
    ACC4(f_, (qv).z, 8);                                                   \
    ACC4(f_, (qv).w, 12);                                                  \
  }

  int j = 0;
  for (; j + 4 <= n; j += 4) {
    unsigned int p0 = sedge[start + j];
    unsigned int p1 = sedge[start + j + 1];
    unsigned int p2 = sedge[start + j + 2];
    unsigned int p3 = sedge[start + j + 3];
    uint4 h0 = GATHER(p0);
    uint4 h1 = GATHER(p1);
    uint4 h2 = GATHER(p2);
    uint4 h3 = GATHER(p3);
    float f0 = FEDGE(p0);
    float f1 = FEDGE(p1);
    float f2 = FEDGE(p2);
    float f3 = FEDGE(p3);
    ACCUM(h0, f0);
    ACCUM(h1, f1);
    ACCUM(h2, f2);
    ACCUM(h3, f3);
  }
  for (; j < n; ++j) {
    unsigned int p = sedge[start + j];
    uint4 hv = GATHER(p);
    ACCUM(hv, FEDGE(p));
  }
#undef GATHER
#undef FEDGE
#undef ACC4
#undef ACCUM

  uint4 o0, o1;
  o0.x = f2b2(acc[0], acc[1]);
  o0.y = f2b2(acc[2], acc[3]);
  o0.z = f2b2(acc[4], acc[5]);
  o0.w = f2b2(acc[6], acc[7]);
  o1.x = f2b2(acc[8], acc[9]);
  o1.y = f2b2(acc[10], acc[11]);
  o1.z = f2b2(acc[12], acc[13]);
  o1.w = f2b2(acc[14], acc[15]);
  uint4* gp = reinterpret_cast<uint4*>(g + (size_t)r * DIM + l * 16);
  gp[0] = o0;
  gp[1] = o1;
}

// == gemm2: out = lrelu( g @ W^T + b + dequant(xq) ), MFMA bf16 =============
__global__ __launch_bounds__(256) void gemm2(
    const unsigned short* __restrict__ g, const unsigned short* __restrict__ Wb,
    const float* __restrict__ b, const unsigned int* __restrict__ xq,
    const float* __restrict__ scale, float* __restrict__ out, int N) {
  __shared__ unsigned short Ws[DIM * DIM];  // 32 KB

  const int t = threadIdx.x;
#pragma unroll
  for (int i = 0; i < 8; ++i) {
    int idx = i * 256 + t;            // 16B-unit index, 0..2047
    int row = idx >> 4;
    int slot = idx & 15;
    uint4 v = reinterpret_cast<const uint4*>(Wb)[idx];
    reinterpret_cast<uint4*>(Ws)[row * 16 + (slot ^ (row & 7))] = v;
  }
  __syncthreads();

  const int wid  = t >> 6;
  const int lane = t & 63;
  const int m0   = blockIdx.x * 64 + wid * 16;
  const int mrow = m0 + (lane & 15);
  const int koff = (lane >> 4) * 8;
  const int arow = (mrow < N) ? mrow : N - 1;

  f32x4 acc[8];
#pragma unroll
  for (int j = 0; j < 8; ++j) acc[j] = (f32x4){0.f, 0.f, 0.f, 0.f};

#pragma unroll
  for (int k0 = 0; k0 < DIM; k0 += 32) {
    bf16x8 af = *reinterpret_cast<const bf16x8*>(g + (size_t)arow * DIM + k0 + koff);
    const int slotbase = (k0 >> 3) + (lane >> 4);
#pragma unroll
    for (int j = 0; j < 8; ++j) {
      int row = j * 16 + (lane & 15);
      const uint4* wp = reinterpret_cast<const uint4*>(Ws) +
                        row * 16 + (slotbase ^ (row & 7));
      bf16x8 bf = *reinterpret_cast<const bf16x8*>(wp);
      acc[j] = __builtin_amdgcn_mfma_f32_16x16x32_bf16(af, bf, acc[j], 0, 0, 0);
    }
  }

  const int rowbase = (lane >> 4) * 4;
  float sq[4];
#pragma unroll
  for (int i = 0; i < 4; ++i) {
    int m = m0 + rowbase + i;
    sq[i] = (m < N) ? scale[m] : 0.f;
  }
#pragma unroll
  for (int j = 0; j < 8; ++j) {
    int n = j * 16 + (lane & 15);
    float bias = b[n];
#pragma unroll
    for (int i = 0; i < 4; ++i) {
      int m = m0 + rowbase + i;
      if (m < N) {
        unsigned int w = xq[(size_t)m * 32 + (n >> 2)];
        float res = (float)(signed char)(w >> ((n & 3) * 8)) * sq[i];
        float v = acc[j][i] + bias + res;
        out[(size_t)m * DIM + n] = v > 0.f ? v : 0.2f * v;
      }
    }
  }
}

// ===========================================================================
extern "C" void kernel_launch(void* const* d_in, const int* in_sizes, int n_in,
                              void* d_out, int out_size, void* d_ws,
                              size_t ws_size, hipStream_t stream) {
  const float* x  = (const float*)d_in[0];
  const int* erow = (const int*)d_in[1];
  const int* ecol = (const int*)d_in[2];
  const float* ew = (const float*)d_in[3];
  const float* W  = (const float*)d_in[4];
  const float* b  = (const float*)d_in[5];
  float* out      = (float*)d_out;

  const int N = in_sizes[0] / DIM;
  const int E = in_sizes[1];
  const int NSB = (N + SB_ROWS - 1) >> SB_SHIFT;  // 196 for N=100000
  const int netile = (E + TILE1 - 1) / TILE1;

  char* wsp = (char*)d_ws;
  unsigned int* xq   = (unsigned int*)wsp;    wsp += (size_t)N * DIM;            // int8
  float* scale = (float*)wsp;                 wsp += (size_t)N * sizeof(float);
  unsigned short* g  = (unsigned short*)wsp;  wsp += (size_t)N * DIM * sizeof(unsigned short);
  int*   off   = (int*)wsp;                   wsp += (size_t)N * sizeof(int);
  int*   deg   = (int*)wsp;                   wsp += (size_t)N * sizeof(int);
  int*   cnt   = (int*)wsp;                   wsp += 4096;
  unsigned short* Wb = (unsigned short*)wsp;  wsp += DIM * DIM * sizeof(unsigned short);
  int2*  gL1   = (int2*)wsp;                  wsp += (size_t)NSB * SBCAP * sizeof(int2);
  unsigned int* sedge = (unsigned int*)wsp;   wsp += (size_t)NSB * SBCAP * sizeof(unsigned int);

  const int nelem8 = N * DIM / 8;
  const int ncw = (DIM * DIM / 8 + 255) / 256;   // 8
  const int nxb = (nelem8 + 255) / 256;
  prep_all<<<ncw + nxb + 1, 256, 0, stream>>>(W, Wb, x, xq, scale, cnt,
                                              nelem8, ncw, nxb);

  part1<<<netile, 512, 0, stream>>>(erow, ecol, ew, cnt, gL1, E, NSB);

  part2<<<NSB, 512, 0, stream>>>(gL1, cnt, off, deg, sedge, N);

  aggregate2<<<(N + 31) / 32, 256, 0, stream>>>(xq, scale, off, deg, sedge, g, N);

  gemm2<<<(N + 63) / 64, 256, 0, stream>>>(g, Wb, b, xq, scale, out, N);
}